// Round 3
// baseline (655.089 us; speedup 1.0000x reference)
//
#include <hip/hip_runtime.h>

// LiDAR volume renderer: N=8192 rays, S=768 steps, 20 semantic + 2 attr channels.
// out[ray][0]=depth, [1:3]=image(attr, masked w>1e-4), [3:23]=semantic, [23]=weights_sum
//
// Reformulation: 1-alpha_s = exp(-x_s), x_s = delta_s*sigma_s, so
// T_i = cumprod(1-a+1e-15) ~= exp(-prefix_sum(x)) (the 1e-15 is relatively ~1e-15).
// => block-parallel scan instead of a sequential cumprod.
//
// R1: transmittance early-exit at T<3e-4 (−20 µs, confirmed kernel is BW-bound).
// R2: raise cut to T<2e-3. Image stays BIT-EXACT: skipped w <= T_cut*alpha_max
//     = 2e-3 * 0.0308 = 6.2e-5 < 1e-4 reference mask threshold.
//     depth/weights_sum exact (phase 1 uses all steps). Semantic tail error
//     std ~4e-4, max ~1.8e-3 < current 0.0039 absmax.
//     + nontemporal loads on the streamed inputs (single-use, no reuse).
// R3: fix compile — __builtin_nontemporal_load needs native clang vector types,
//     not HIP_vector_type. Use ext_vector_type typedefs.

#define NSTEPS 768
#define NSEM 20
#define NOUT 24

typedef float f32x4 __attribute__((ext_vector_type(4)));
typedef float f32x2 __attribute__((ext_vector_type(2)));

static constexpr float kNear = 0.01f;
static constexpr float kFar  = 0.81f;
static constexpr float kWThresh = 1e-4f;
static constexpr float kLogTCut = 6.214608f;   // -ln(2e-3)

__global__ __launch_bounds__(256) void lidar_render_kernel(
    const float* __restrict__ sigma,   // [N, S]
    const float* __restrict__ sem,     // [N, S, 20]
    const float* __restrict__ attr,    // [N, S, 2]
    float* __restrict__ out)           // [N, 24]
{
    const int ray  = blockIdx.x;
    const int t    = threadIdx.x;
    const int lane = t & 63;
    const int wave = t >> 6;

    __shared__ float w_lds[NSTEPS];      // weights
    __shared__ float wave_tot[4];
    __shared__ int   cnt_lds[4];         // per-wave count of threads with T >= T_cut
    __shared__ float red[4][NOUT];

    // ---------------- Phase 1: weights via exp(-prefix sum) ----------------
    const float h  = (kFar - kNear) / (float)(NSTEPS - 1); // delta for s < S-1
    const float h2 = (kFar - kNear) / (float)NSTEPS;       // last delta
    const float zstep = (kFar - kNear) / (float)(NSTEPS - 1);

    const int s0 = 3 * t;                       // this thread owns steps s0..s0+2
    const float* sp = sigma + (size_t)ray * NSTEPS + s0;
    float sg0 = __builtin_nontemporal_load(sp);
    float sg1 = __builtin_nontemporal_load(sp + 1);
    float sg2 = __builtin_nontemporal_load(sp + 2);
    float x0 = h * sg0;
    float x1 = h * sg1;
    float x2 = ((s0 + 2) == (NSTEPS - 1) ? h2 : h) * sg2;
    float local = x0 + x1 + x2;

    // wave-inclusive scan of per-thread sums
    float inc = local;
    #pragma unroll
    for (int d = 1; d < 64; d <<= 1) {
        float v = __shfl_up(inc, d, 64);
        if (lane >= d) inc += v;
    }
    if (lane == 63) wave_tot[wave] = inc;
    __syncthreads();
    float base = inc - local;                   // exclusive within wave
    #pragma unroll
    for (int wv = 0; wv < 4; ++wv)
        if (wv < wave) base += wave_tot[wv];

    float T  = __expf(-base);
    float e0 = __expf(-x0), e1 = __expf(-x1), e2 = __expf(-x2);
    float w0 = T * (1.0f - e0);  T *= e0;
    float w1 = T * (1.0f - e1);  T *= e1;
    float w2 = T * (1.0f - e2);

    w_lds[s0]     = w0;
    w_lds[s0 + 1] = w1;
    w_lds[s0 + 2] = w2;

    // depth & weights_sum from ALL steps (exact — unaffected by the early exit)
    const float z0 = kNear + zstep * (float)s0;
    float depth_p = w0 * z0 + w1 * (z0 + zstep) + w2 * (z0 + 2.0f * zstep);
    float wsum_p  = w0 + w1 + w2;

    // early-exit cut: base is monotone nondecreasing in t, so the set
    // {base < kLogTCut} is a prefix of threads; count it with a ballot.
    unsigned long long live = __ballot(base < kLogTCut);
    if (lane == 0) cnt_lds[wave] = __popcll(live);
    __syncthreads();

    const int s_cut = 3 * (cnt_lds[0] + cnt_lds[1] + cnt_lds[2] + cnt_lds[3]);

    // ---------------- Phase 2: weighted channel reductions ----------------
    float acc_sem[NSEM];
    #pragma unroll
    for (int k = 0; k < NSEM; ++k) acc_sem[k] = 0.0f;
    float acc_im0 = 0.0f, acc_im1 = 0.0f;

    const float* semp = sem  + (size_t)ray * NSTEPS * NSEM;
    const float* attp = attr + (size_t)ray * NSTEPS * 2;

    #pragma unroll
    for (int i = 0; i < 3; ++i) {
        const int s = t + 256 * i;
        if (s < s_cut) {
            const float w = w_lds[s];
            const f32x4* p4 = (const f32x4*)(semp + (size_t)s * NSEM);
            #pragma unroll
            for (int j = 0; j < 5; ++j) {
                f32x4 v = __builtin_nontemporal_load(p4 + j);
                acc_sem[4 * j + 0] += w * v.x;
                acc_sem[4 * j + 1] += w * v.y;
                acc_sem[4 * j + 2] += w * v.z;
                acc_sem[4 * j + 3] += w * v.w;
            }
            f32x2 a2 = __builtin_nontemporal_load((const f32x2*)(attp + (size_t)s * 2));
            if (w > kWThresh) {
                acc_im0 += w * a2.x;
                acc_im1 += w * a2.y;
            }
        }
    }

    // ---------------- Phase 3: reduce 24 values across the block ----------------
    float vals[NOUT];
    vals[0] = depth_p;
    vals[1] = acc_im0;
    vals[2] = acc_im1;
    #pragma unroll
    for (int k = 0; k < NSEM; ++k) vals[3 + k] = acc_sem[k];
    vals[23] = wsum_p;

    #pragma unroll
    for (int j = 0; j < NOUT; ++j) {
        float v = vals[j];
        #pragma unroll
        for (int d = 32; d >= 1; d >>= 1) v += __shfl_xor(v, d, 64);
        vals[j] = v;
    }
    if (lane == 0) {
        #pragma unroll
        for (int j = 0; j < NOUT; ++j) red[wave][j] = vals[j];
    }
    __syncthreads();
    if (t < NOUT) {
        out[(size_t)ray * NOUT + t] = red[0][t] + red[1][t] + red[2][t] + red[3][t];
    }
}

extern "C" void kernel_launch(void* const* d_in, const int* in_sizes, int n_in,
                              void* d_out, int out_size, void* d_ws, size_t ws_size,
                              hipStream_t stream) {
    const float* sigma = (const float*)d_in[0];   // [8192, 768]
    const float* sem   = (const float*)d_in[1];   // [8192, 768, 20]
    const float* attr  = (const float*)d_in[2];   // [8192, 768, 2]
    float* out = (float*)d_out;                   // [8192, 24]

    const int n_rays = in_sizes[0] / NSTEPS;
    lidar_render_kernel<<<n_rays, 256, 0, stream>>>(sigma, sem, attr, out);
}

// Round 4
// 636.270 us; speedup vs baseline: 1.0296x; 1.0296x over previous
//
#include <hip/hip_runtime.h>

// LiDAR volume renderer: N=8192 rays, S=768 steps, 20 semantic + 2 attr channels.
// out[ray][0]=depth, [1:3]=image(attr, masked w>1e-4), [3:23]=semantic, [23]=weights_sum
//
// Reformulation: 1-alpha_s = exp(-x_s), x_s = delta_s*sigma_s, so
// T_i = cumprod(1-a+1e-15) ~= exp(-prefix_sum(x)) (the 1e-15 is relatively ~1e-15).
// => block-parallel scan instead of a sequential cumprod.
//
// R1: transmittance early-exit at T<3e-4 (−20 µs, confirmed kernel BW-sensitivity).
// R2/R3: cut raised to T<2e-3 (image still BIT-EXACT: skipped w <= 2e-3*0.0308
//     = 6.2e-5 < 1e-4 mask thresh) + NT loads. NET NULL — two changes bundled.
// R4: A/B — revert NT loads only, keep the 2e-3 cut. NT suspected of offsetting
//     the cut's gain (no L2/L3 allocate + broke dwordx3 merge on sigma loads).

#define NSTEPS 768
#define NSEM 20
#define NOUT 24

static constexpr float kNear = 0.01f;
static constexpr float kFar  = 0.81f;
static constexpr float kWThresh = 1e-4f;
static constexpr float kLogTCut = 6.214608f;   // -ln(2e-3)

__global__ __launch_bounds__(256) void lidar_render_kernel(
    const float* __restrict__ sigma,   // [N, S]
    const float* __restrict__ sem,     // [N, S, 20]
    const float* __restrict__ attr,    // [N, S, 2]
    float* __restrict__ out)           // [N, 24]
{
    const int ray  = blockIdx.x;
    const int t    = threadIdx.x;
    const int lane = t & 63;
    const int wave = t >> 6;

    __shared__ float w_lds[NSTEPS];      // weights
    __shared__ float wave_tot[4];
    __shared__ int   cnt_lds[4];         // per-wave count of threads with T >= T_cut
    __shared__ float red[4][NOUT];

    // ---------------- Phase 1: weights via exp(-prefix sum) ----------------
    const float h  = (kFar - kNear) / (float)(NSTEPS - 1); // delta for s < S-1
    const float h2 = (kFar - kNear) / (float)NSTEPS;       // last delta
    const float zstep = (kFar - kNear) / (float)(NSTEPS - 1);

    const int s0 = 3 * t;                       // this thread owns steps s0..s0+2
    const float* sp = sigma + (size_t)ray * NSTEPS + s0;
    float sg0 = sp[0], sg1 = sp[1], sg2 = sp[2];
    float x0 = h * sg0;
    float x1 = h * sg1;
    float x2 = ((s0 + 2) == (NSTEPS - 1) ? h2 : h) * sg2;
    float local = x0 + x1 + x2;

    // wave-inclusive scan of per-thread sums
    float inc = local;
    #pragma unroll
    for (int d = 1; d < 64; d <<= 1) {
        float v = __shfl_up(inc, d, 64);
        if (lane >= d) inc += v;
    }
    if (lane == 63) wave_tot[wave] = inc;
    __syncthreads();
    float base = inc - local;                   // exclusive within wave
    #pragma unroll
    for (int wv = 0; wv < 4; ++wv)
        if (wv < wave) base += wave_tot[wv];

    float T  = __expf(-base);
    float e0 = __expf(-x0), e1 = __expf(-x1), e2 = __expf(-x2);
    float w0 = T * (1.0f - e0);  T *= e0;
    float w1 = T * (1.0f - e1);  T *= e1;
    float w2 = T * (1.0f - e2);

    w_lds[s0]     = w0;
    w_lds[s0 + 1] = w1;
    w_lds[s0 + 2] = w2;

    // depth & weights_sum from ALL steps (exact — unaffected by the early exit)
    const float z0 = kNear + zstep * (float)s0;
    float depth_p = w0 * z0 + w1 * (z0 + zstep) + w2 * (z0 + 2.0f * zstep);
    float wsum_p  = w0 + w1 + w2;

    // early-exit cut: base is monotone nondecreasing in t, so the set
    // {base < kLogTCut} is a prefix of threads; count it with a ballot.
    unsigned long long live = __ballot(base < kLogTCut);
    if (lane == 0) cnt_lds[wave] = __popcll(live);
    __syncthreads();

    const int s_cut = 3 * (cnt_lds[0] + cnt_lds[1] + cnt_lds[2] + cnt_lds[3]);

    // ---------------- Phase 2: weighted channel reductions ----------------
    float acc_sem[NSEM];
    #pragma unroll
    for (int k = 0; k < NSEM; ++k) acc_sem[k] = 0.0f;
    float acc_im0 = 0.0f, acc_im1 = 0.0f;

    const float* semp = sem  + (size_t)ray * NSTEPS * NSEM;
    const float* attp = attr + (size_t)ray * NSTEPS * 2;

    #pragma unroll
    for (int i = 0; i < 3; ++i) {
        const int s = t + 256 * i;
        if (s < s_cut) {
            const float w = w_lds[s];
            const float4* p4 = (const float4*)(semp + (size_t)s * NSEM);
            #pragma unroll
            for (int j = 0; j < 5; ++j) {
                float4 v = p4[j];
                acc_sem[4 * j + 0] += w * v.x;
                acc_sem[4 * j + 1] += w * v.y;
                acc_sem[4 * j + 2] += w * v.z;
                acc_sem[4 * j + 3] += w * v.w;
            }
            float2 a2 = *(const float2*)(attp + (size_t)s * 2);
            if (w > kWThresh) {
                acc_im0 += w * a2.x;
                acc_im1 += w * a2.y;
            }
        }
    }

    // ---------------- Phase 3: reduce 24 values across the block ----------------
    float vals[NOUT];
    vals[0] = depth_p;
    vals[1] = acc_im0;
    vals[2] = acc_im1;
    #pragma unroll
    for (int k = 0; k < NSEM; ++k) vals[3 + k] = acc_sem[k];
    vals[23] = wsum_p;

    #pragma unroll
    for (int j = 0; j < NOUT; ++j) {
        float v = vals[j];
        #pragma unroll
        for (int d = 32; d >= 1; d >>= 1) v += __shfl_xor(v, d, 64);
        vals[j] = v;
    }
    if (lane == 0) {
        #pragma unroll
        for (int j = 0; j < NOUT; ++j) red[wave][j] = vals[j];
    }
    __syncthreads();
    if (t < NOUT) {
        out[(size_t)ray * NOUT + t] = red[0][t] + red[1][t] + red[2][t] + red[3][t];
    }
}

extern "C" void kernel_launch(void* const* d_in, const int* in_sizes, int n_in,
                              void* d_out, int out_size, void* d_ws, size_t ws_size,
                              hipStream_t stream) {
    const float* sigma = (const float*)d_in[0];   // [8192, 768]
    const float* sem   = (const float*)d_in[1];   // [8192, 768, 20]
    const float* attr  = (const float*)d_in[2];   // [8192, 768, 2]
    float* out = (float*)d_out;                   // [8192, 24]

    const int n_rays = in_sizes[0] / NSTEPS;
    lidar_render_kernel<<<n_rays, 256, 0, stream>>>(sigma, sem, attr, out);
}